// Round 1
// baseline (236.703 us; speedup 1.0000x reference)
//
#include <hip/hip_runtime.h>
#include <hip/hip_bf16.h>

#define BDIM 4096
#define DDIM 1024
#define NPAIRS 5
#define TW 16            // 4096/256 tiles per side
#define NH 32            // 1024/32 half-K steps
#define HBUF 8192        // shorts per half-K buffer per matrix (256*32)

typedef __attribute__((ext_vector_type(8))) short short8;
typedef __attribute__((ext_vector_type(4))) float floatx4;

__device__ __forceinline__ void gload16(const void* g, void* l) {
    __builtin_amdgcn_global_load_lds((const __attribute__((address_space(1))) void*)g,
                                     (__attribute__((address_space(3))) void*)l, 16, 0, 0);
}

__device__ __forceinline__ unsigned short f2bf(float f) {
    unsigned u = __float_as_uint(f);
    u = (u + 0x7FFFu + ((u >> 16) & 1u)) >> 16;   // RNE f32->bf16
    return (unsigned short)u;
}

// ---------------- cast f32 -> bf16, 4 matrices ----------------
__global__ void cast_kernel(const float* __restrict__ t, const float* __restrict__ im,
                            const float* __restrict__ au, const float* __restrict__ de,
                            short* __restrict__ out) {
    const float* src;
    switch (blockIdx.y) {
        case 0: src = t; break;
        case 1: src = im; break;
        case 2: src = au; break;
        default: src = de; break;
    }
    short* dst = out + (size_t)blockIdx.y * (BDIM * DDIM);
    int idx = (blockIdx.x * 256 + threadIdx.x) * 8;
    float4 f0 = *(const float4*)(src + idx);
    float4 f1 = *(const float4*)(src + idx + 4);
    short8 r;
    r[0] = (short)f2bf(f0.x); r[1] = (short)f2bf(f0.y);
    r[2] = (short)f2bf(f0.z); r[3] = (short)f2bf(f0.w);
    r[4] = (short)f2bf(f1.x); r[5] = (short)f2bf(f1.y);
    r[6] = (short)f2bf(f1.z); r[7] = (short)f2bf(f1.w);
    *(short8*)(dst + idx) = r;
}

// ---- stage one 256x32 half-K tile: linear LDS dest, inverse-swizzled global src.
// Linear byte off = i*8192 + w*1024 + l*16  ->  row = i*128 + w*16 + (l>>2),
// phys slot = l&3, logical slot = (l&3) ^ (row&3) = (l&3) ^ ((l>>2)&3).
// Exactly 2 vmcnt ops per call (counted by the pipeline vmcnt ledger).
__device__ __forceinline__ void stage_half(const short* __restrict__ gsrc, short* ldst,
                                           int w, int l, int k0) {
    const int r0 = w * 16 + (l >> 2);
    const int kof = ((l & 3) ^ ((l >> 2) & 3)) * 8;
#pragma unroll
    for (int i = 0; i < 2; ++i) {
        int row = i * 128 + r0;
        gload16(gsrc + (size_t)row * DDIM + k0 + kof,
                (char*)ldst + i * 8192 + w * 1024 + l * 16);
    }
}

// swizzled ds_read of an 8-bf16 fragment at logical (row, kofShorts) in a 256x32 buffer
// rows are 64 B, 4 x 16B slots, slot ^= row&3  -> 8 lanes per 4-bank group: conflict-free
__device__ __forceinline__ short8 ldsfrag32(const short* buf, int row, int kofShorts) {
    int slot = kofShorts >> 3;
    return *(const short8*)((const char*)buf + row * 64 + ((slot ^ (row & 3)) << 4));
}

// constant-index select for a dynamic lane of a floatx4 (avoids dynamic GEP)
__device__ __forceinline__ float vsel4(floatx4 v, int j) {
    return (j == 0) ? v[0] : (j == 1) ? v[1] : (j == 2) ? v[2] : v[3];
}

// one half-K step: ds_read frags  ||  issue next stage loads  ||  2 setprio MFMA clusters
// All acc[][] indices compile-time constant after unroll (rule #20).
__device__ __forceinline__ void khalf(floatx4 (&acc)[8][4],
                                      const short* a_buf, const short* b_buf,
                                      short* a_nxt, short* b_nxt,
                                      const short* __restrict__ Aop,
                                      const short* __restrict__ Bop,
                                      int w, int l, int arow, int brow, int hi,
                                      int k0n, bool doStage) {
    short8 bfr[4];
#pragma unroll
    for (int n = 0; n < 4; ++n) bfr[n] = ldsfrag32(b_buf, brow + n * 16, hi * 8);
    short8 afr[4];
#pragma unroll
    for (int m = 0; m < 4; ++m) afr[m] = ldsfrag32(a_buf, arow + m * 16, hi * 8);
    if (doStage) stage_half(Aop, a_nxt, w, l, k0n);   // 2 vmcnt ops
    __builtin_amdgcn_s_setprio(1);
#pragma unroll
    for (int m = 0; m < 4; ++m)
#pragma unroll
        for (int n = 0; n < 4; ++n)
            acc[m][n] = __builtin_amdgcn_mfma_f32_16x16x32_bf16(afr[m], bfr[n], acc[m][n], 0, 0, 0);
    __builtin_amdgcn_s_setprio(0);
#pragma unroll
    for (int m = 0; m < 4; ++m) afr[m] = ldsfrag32(a_buf, arow + (m + 4) * 16, hi * 8);
    if (doStage) stage_half(Bop, b_nxt, w, l, k0n);   // 2 vmcnt ops
    __builtin_amdgcn_s_setprio(1);
#pragma unroll
    for (int m = 0; m < 4; ++m)
#pragma unroll
        for (int n = 0; n < 4; ++n)
            acc[m + 4][n] = __builtin_amdgcn_mfma_f32_16x16x32_bf16(afr[m], bfr[n], acc[m + 4][n], 0, 0, 0);
    __builtin_amdgcn_s_setprio(0);
}

// ---------------- fused 256^2 GEMM + per-tile partial LSE ----------------
// grid: 1280 blocks (16x16 tiles x 5 pairs), 512 threads (8 waves, 2M x 4N)
// T3+T4 pipeline: 4 half-K (256x32) buffers per matrix, 3 halves prefetched ahead,
// counted s_waitcnt vmcnt(8) per iteration — never drained to 0 in the main loop.
// vmcnt ledger: exactly 4 loads/iter issued in order A,A,B,B; no other vector-mem
// ops in the loop (scale is read AFTER the loop so it cannot shift the count).
__launch_bounds__(512, 1)
__global__ void gemm_lse_kernel(const short* __restrict__ mats, const float* __restrict__ scale_p,
                                float* __restrict__ rowpart, float* __restrict__ colpart,
                                float* __restrict__ diag) {
    extern __shared__ char smem[];
    short* As = (short*)smem;                         // [4][8192] half-K buffers
    short* Bs = (short*)(smem + 65536);               // [4][8192]
    float* rowLse = (float*)(smem + 131072);          // [4][256]
    float* colLse = rowLse + 4 * 256;                 // [2][256]

    const int tid = threadIdx.x;
    const int w = tid >> 6, l = tid & 63;
    const int wr = w >> 2, wc = w & 3;

    // bijective XCD swizzle: nwg = 1280 = 8 * 160
    const int orig = blockIdx.x;
    const int swz = (orig & 7) * 160 + (orig >> 3);
    const int p = swz >> 8;           // pair 0..4
    const int t = swz & 255;
    const int tileRow = t & 15, tileCol = t >> 4;

    // mats order: text(0) image(1) audio(2) depth(3); no stack arrays (rule #20)
    int ai, bi;
    switch (p) {
        case 0: ai = 2; bi = 0; break;
        case 1: ai = 2; bi = 1; break;
        case 2: ai = 3; bi = 0; break;
        case 3: ai = 3; bi = 1; break;
        default: ai = 0; bi = 1; break;
    }
    const short* Aop = mats + (size_t)ai * (BDIM * DDIM) + tileRow * 256 * DDIM;
    const short* Bop = mats + (size_t)bi * (BDIM * DDIM) + tileCol * 256 * DDIM;

    floatx4 acc[8][4];
#pragma unroll
    for (int m = 0; m < 8; ++m)
#pragma unroll
        for (int n = 0; n < 4; ++n) acc[m][n] = (floatx4)(0.f);

    const int fr = l & 15, hi = l >> 4;
    const int arow = wr * 128 + fr;   // + m*16
    const int brow = wc * 64 + fr;    // + n*16

    // prologue: stage halves 0,1,2  -> 12 loads in flight; half 0 = oldest 4
    stage_half(Aop, As + 0 * HBUF, w, l, 0);
    stage_half(Bop, Bs + 0 * HBUF, w, l, 0);
    stage_half(Aop, As + 1 * HBUF, w, l, 32);
    stage_half(Bop, Bs + 1 * HBUF, w, l, 32);
    stage_half(Aop, As + 2 * HBUF, w, l, 64);
    stage_half(Bop, Bs + 2 * HBUF, w, l, 64);
    asm volatile("s_waitcnt vmcnt(8)" ::: "memory");
    __builtin_amdgcn_s_barrier();

    // main loop: h = 0..27, always stage h+3 (<=30), keep 8 loads in flight across barrier
#pragma unroll 4
    for (int h = 0; h < 28; ++h) {
        const int hb = h & 3, nb = (h + 3) & 3;
        khalf(acc, As + hb * HBUF, Bs + hb * HBUF, As + nb * HBUF, Bs + nb * HBUF,
              Aop, Bop, w, l, arow, brow, hi, (h + 3) * 32, true);
        asm volatile("s_waitcnt vmcnt(8)" ::: "memory");  // half h+1 done; h+2,h+3 in flight
        __builtin_amdgcn_s_barrier();
    }
    // h = 28: stage half 31 (last), then drain 8 -> 4 -> 0 over the tail
    khalf(acc, As + 0 * HBUF, Bs + 0 * HBUF, As + 3 * HBUF, Bs + 3 * HBUF,
          Aop, Bop, w, l, arow, brow, hi, 31 * 32, true);
    asm volatile("s_waitcnt vmcnt(8)" ::: "memory");      // half 29 done
    __builtin_amdgcn_s_barrier();
    // h = 29
    khalf(acc, As + 1 * HBUF, Bs + 1 * HBUF, As + 0 * HBUF, Bs + 0 * HBUF,
          Aop, Bop, w, l, arow, brow, hi, 0, false);
    asm volatile("s_waitcnt vmcnt(4)" ::: "memory");      // half 30 done
    __builtin_amdgcn_s_barrier();
    // h = 30
    khalf(acc, As + 2 * HBUF, Bs + 2 * HBUF, As + 0 * HBUF, Bs + 0 * HBUF,
          Aop, Bop, w, l, arow, brow, hi, 0, false);
    asm volatile("s_waitcnt vmcnt(0)" ::: "memory");      // half 31 done
    __builtin_amdgcn_s_barrier();
    // h = 31
    khalf(acc, As + 3 * HBUF, Bs + 3 * HBUF, As + 0 * HBUF, Bs + 0 * HBUF,
          Aop, Bop, w, l, arow, brow, hi, 0, false);

    // scale (read AFTER the K-loop so no stray vector-mem op disturbs vmcnt counting)
    const float s = scale_p[0];
#pragma unroll
    for (int m = 0; m < 8; ++m)
#pragma unroll
        for (int n = 0; n < 4; ++n)
#pragma unroll
            for (int j = 0; j < 4; ++j) acc[m][n][j] *= s;

    // C/D layout: out[A-row: m*16+hi*4+j][B-row: n*16+fr] = acc[m][n][j]

    // ---- row partial LSE over this wave's 64 cols ----
#pragma unroll
    for (int m = 0; m < 8; ++m) {
#pragma unroll
        for (int j = 0; j < 4; ++j) {
            float mx = -3.0e38f;
#pragma unroll
            for (int n = 0; n < 4; ++n) mx = fmaxf(mx, acc[m][n][j]);
#pragma unroll
            for (int off = 1; off < 16; off <<= 1) mx = fmaxf(mx, __shfl_xor(mx, off));
            float sm = 0.f;
#pragma unroll
            for (int n = 0; n < 4; ++n) sm += __expf(acc[m][n][j] - mx);
#pragma unroll
            for (int off = 1; off < 16; off <<= 1) sm += __shfl_xor(sm, off);
            if (fr == 0)
                rowLse[wc * 256 + wr * 128 + m * 16 + hi * 4 + j] = mx + __logf(sm);
        }
    }

    // ---- col partial LSE over this wave's 128 rows ----
#pragma unroll
    for (int n = 0; n < 4; ++n) {
        float mx = -3.0e38f;
#pragma unroll
        for (int m = 0; m < 8; ++m)
#pragma unroll
            for (int j = 0; j < 4; ++j) mx = fmaxf(mx, acc[m][n][j]);
        mx = fmaxf(mx, __shfl_xor(mx, 16));
        mx = fmaxf(mx, __shfl_xor(mx, 32));
        float sm = 0.f;
#pragma unroll
        for (int m = 0; m < 8; ++m)
#pragma unroll
            for (int j = 0; j < 4; ++j) sm += __expf(acc[m][n][j] - mx);
        sm += __shfl_xor(sm, 16);
        sm += __shfl_xor(sm, 32);
        if (hi == 0)
            colLse[wr * 256 + wc * 64 + n * 16 + fr] = mx + __logf(sm);
    }

    // ---- diagonal: all acc[] array indices compile-time constant ----
    if (tileRow == tileCol && (wc >> 1) == wr) {
        if (hi == (fr >> 2)) {
            const int j = fr & 3;   // dynamic VECTOR lane only (select chain)
            float* dst = diag + p * BDIM + tileRow * 256 + wc * 64 + fr;
            if ((wc & 1) == 0) {
                dst[0]  = vsel4(acc[0][0], j);
                dst[16] = vsel4(acc[1][1], j);
                dst[32] = vsel4(acc[2][2], j);
                dst[48] = vsel4(acc[3][3], j);
            } else {
                dst[0]  = vsel4(acc[4][0], j);
                dst[16] = vsel4(acc[5][1], j);
                dst[32] = vsel4(acc[6][2], j);
                dst[48] = vsel4(acc[7][3], j);
            }
        }
    }

    __syncthreads();

    // combine partials: threads 0-255 rows, 256-511 cols
    if (tid < 256) {
        float v0 = rowLse[tid], v1 = rowLse[256 + tid], v2 = rowLse[512 + tid], v3 = rowLse[768 + tid];
        float mm = fmaxf(fmaxf(v0, v1), fmaxf(v2, v3));
        float r = mm + __logf(__expf(v0 - mm) + __expf(v1 - mm) + __expf(v2 - mm) + __expf(v3 - mm));
        rowpart[((size_t)p * BDIM + tileRow * 256 + tid) * TW + tileCol] = r;
    } else {
        int c = tid - 256;
        float v0 = colLse[c], v1 = colLse[256 + c];
        float mm = fmaxf(v0, v1);
        float r = mm + __logf(__expf(v0 - mm) + __expf(v1 - mm));
        colpart[((size_t)p * BDIM + tileCol * 256 + c) * TW + tileRow] = r;
    }
}

// ---------------- per-row final LSE + loss partial sums ----------------
__global__ void reduce_kernel(const float* __restrict__ rowpart, const float* __restrict__ colpart,
                              const float* __restrict__ diag, float* __restrict__ partials) {
    int p = blockIdx.y;
    int i = blockIdx.x * 256 + threadIdx.x;
    size_t gi = (size_t)p * BDIM + i;

    const float* rp = rowpart + gi * TW;
    float mx = -3.0e38f;
#pragma unroll
    for (int t = 0; t < TW; ++t) mx = fmaxf(mx, rp[t]);
    float sm = 0.f;
#pragma unroll
    for (int t = 0; t < TW; ++t) sm += __expf(rp[t] - mx);
    float rl = mx + __logf(sm);

    const float* cp = colpart + gi * TW;
    mx = -3.0e38f;
#pragma unroll
    for (int t = 0; t < TW; ++t) mx = fmaxf(mx, cp[t]);
    sm = 0.f;
#pragma unroll
    for (int t = 0; t < TW; ++t) sm += __expf(cp[t] - mx);
    float cl = mx + __logf(sm);

    float contrib = rl + cl - 2.f * diag[gi];

    __shared__ float red[256];
    red[threadIdx.x] = contrib;
    __syncthreads();
    for (int s2 = 128; s2 > 0; s2 >>= 1) {
        if (threadIdx.x < (unsigned)s2) red[threadIdx.x] += red[threadIdx.x + s2];
        __syncthreads();
    }
    if (threadIdx.x == 0) partials[p * 16 + blockIdx.x] = red[0];
}

__global__ void final_kernel(const float* __restrict__ partials, float* __restrict__ out) {
    __shared__ float red[128];
    int t = threadIdx.x;
    red[t] = (t < NPAIRS * 16) ? partials[t] : 0.f;
    __syncthreads();
    for (int s2 = 64; s2 > 0; s2 >>= 1) {
        if (t < s2) red[t] += red[t + s2];
        __syncthreads();
    }
    if (t == 0) out[0] = red[0] * (1.f / (2.f * BDIM));
}

extern "C" void kernel_launch(void* const* d_in, const int* in_sizes, int n_in,
                              void* d_out, int out_size, void* d_ws, size_t ws_size,
                              hipStream_t stream) {
    const float* text  = (const float*)d_in[0];
    const float* image = (const float*)d_in[1];
    const float* audio = (const float*)d_in[2];
    const float* depth = (const float*)d_in[3];
    const float* scale = (const float*)d_in[4];
    float* out = (float*)d_out;

    char* ws = (char*)d_ws;
    short* mats = (short*)ws;                                   // 4 * 8 MB bf16
    size_t off = (size_t)4 * BDIM * DDIM * 2;
    float* rowpart = (float*)(ws + off); off += (size_t)NPAIRS * BDIM * TW * 4;
    float* colpart = (float*)(ws + off); off += (size_t)NPAIRS * BDIM * TW * 4;
    float* diag    = (float*)(ws + off); off += (size_t)NPAIRS * BDIM * 4;
    float* partials= (float*)(ws + off); off += NPAIRS * 16 * 4;

    const int smem_bytes = 131072 + 4 * 256 * 4 + 2 * 256 * 4;  // 137216
    hipFuncSetAttribute((const void*)gemm_lse_kernel,
                        hipFuncAttributeMaxDynamicSharedMemorySize, smem_bytes);

    cast_kernel<<<dim3(2048, 4), 256, 0, stream>>>(text, image, audio, depth, mats);
    gemm_lse_kernel<<<dim3(1280), 512, smem_bytes, stream>>>(mats, scale, rowpart, colpart, diag);
    reduce_kernel<<<dim3(16, NPAIRS), 256, 0, stream>>>(rowpart, colpart, diag, partials);
    final_kernel<<<1, 128, 0, stream>>>(partials, out);
}

// Round 2
// 234.197 us; speedup vs baseline: 1.0107x; 1.0107x over previous
//
#include <hip/hip_runtime.h>
#include <hip/hip_bf16.h>

#define BDIM 4096
#define DDIM 1024
#define NPAIRS 5
#define TW 16            // 4096/256 tiles per side
#define KT 16            // 1024/64 K-tiles
#define RSH 8192         // shorts per 256x32 region

typedef __attribute__((ext_vector_type(8))) short short8;
typedef __attribute__((ext_vector_type(4))) float floatx4;

__device__ __forceinline__ void gload16(const void* g, void* l) {
    __builtin_amdgcn_global_load_lds((const __attribute__((address_space(1))) void*)g,
                                     (__attribute__((address_space(3))) void*)l, 16, 0, 0);
}

__device__ __forceinline__ unsigned short f2bf(float f) {
    unsigned u = __float_as_uint(f);
    u = (u + 0x7FFFu + ((u >> 16) & 1u)) >> 16;   // RNE f32->bf16
    return (unsigned short)u;
}

// ---------------- cast f32 -> bf16, 4 matrices ----------------
__global__ void cast_kernel(const float* __restrict__ t, const float* __restrict__ im,
                            const float* __restrict__ au, const float* __restrict__ de,
                            short* __restrict__ out) {
    const float* src;
    switch (blockIdx.y) {
        case 0: src = t; break;
        case 1: src = im; break;
        case 2: src = au; break;
        default: src = de; break;
    }
    short* dst = out + (size_t)blockIdx.y * (BDIM * DDIM);
    int idx = (blockIdx.x * 256 + threadIdx.x) * 8;
    float4 f0 = *(const float4*)(src + idx);
    float4 f1 = *(const float4*)(src + idx + 4);
    short8 r;
    r[0] = (short)f2bf(f0.x); r[1] = (short)f2bf(f0.y);
    r[2] = (short)f2bf(f0.z); r[3] = (short)f2bf(f0.w);
    r[4] = (short)f2bf(f1.x); r[5] = (short)f2bf(f1.y);
    r[6] = (short)f2bf(f1.z); r[7] = (short)f2bf(f1.w);
    *(short8*)(dst + idx) = r;
}

// ---- stage one 256x32 region: linear LDS dest, inverse-swizzled global source.
// Linear byte off = i*8192 + w*1024 + l*16 -> row = i*128 + w*16 + (l>>2), phys slot = l&3.
// Logical k-chunk stored at phys slot p of row r is p ^ ((r>>1)&3)  (bit1 of row,
// since bit0 already flips the bank half via row*64) -> source kof = (l&3)^((l>>3)&3).
// Exactly 2 vmcnt ops per call (the pipeline vmcnt ledger counts these).
__device__ __forceinline__ void stage_region(const short* __restrict__ gsrc, short* reg,
                                             int w, int l, int k0) {
    const int r0 = w * 16 + (l >> 2);
    const int kof = ((l & 3) ^ ((l >> 3) & 3)) * 8;
#pragma unroll
    for (int i = 0; i < 2; ++i) {
        gload16(gsrc + (size_t)(i * 128 + r0) * DDIM + k0 + kof,
                (char*)reg + i * 8192 + w * 1024 + l * 16);
    }
}

// swizzled ds_read of an 8-bf16 fragment at logical (row, 16B-slot hi) in a 256x32 region.
// 64B rows, phys slot = hi ^ ((row>>1)&3): per 16-lane group (16 consecutive rows,
// fixed hi) -> 2 lanes per 4-bank group = 2-way = free (m136). Round-1's row&3 was 4-way.
__device__ __forceinline__ short8 ldsfrag32(const short* reg, int row, int hi) {
    return *(const short8*)((const char*)reg + row * 64 + ((hi ^ ((row >> 1) & 3)) << 4));
}

// constant-index select for a dynamic lane of a floatx4 (avoids dynamic GEP)
__device__ __forceinline__ float vsel4(floatx4 v, int j) {
    return (j == 0) ? v[0] : (j == 1) ? v[1] : (j == 2) ? v[2] : v[3];
}

#define SBAR()  do { __builtin_amdgcn_sched_barrier(0); __builtin_amdgcn_s_barrier(); } while (0)
#define WAITVL(vm) do { asm volatile("s_waitcnt vmcnt(" #vm ") lgkmcnt(0)" ::: "memory"); \
                        __builtin_amdgcn_sched_barrier(0); } while (0)
#define WAITL() do { asm volatile("s_waitcnt lgkmcnt(0)" ::: "memory"); \
                     __builtin_amdgcn_sched_barrier(0); } while (0)

// 16 MFMA cluster: one n-half (NB = 0 or 2) x full m x one k-region. All acc indices
// compile-time constant after unroll (rule #20).
#define MFMA8x2(NB) do { __builtin_amdgcn_s_setprio(1); \
    _Pragma("unroll") for (int m_ = 0; m_ < 8; ++m_) { \
        acc[m_][NB]     = __builtin_amdgcn_mfma_f32_16x16x32_bf16(afr[m_], b0, acc[m_][NB], 0, 0, 0); \
        acc[m_][NB + 1] = __builtin_amdgcn_mfma_f32_16x16x32_bf16(afr[m_], b1, acc[m_][NB + 1], 0, 0, 0); } \
    __builtin_amdgcn_s_setprio(0); } while (0)

// One K-tile = 4 phases. Region death -> stage schedule (2 tiles ahead, same buffer):
//   p0 reads A0(T),B0(T); stages B1(T+1)   (dies at T's p3 two tiles ago)
//   p1 reads B0(T) nh1;   stages A0(T+2)   (A0(T) died after p0)
//   p2 reads A1(T),B1(T); stages B0(T+2)   (B0(T) died after p1)
//   p3 reads B1(T) nh1;   stages A1(T+2)   (A1(T) died after p2)
// Ledger (2 loads/region): wait at p0 retires through B1(T) (covers p2/p3 reads);
// wait at p2 retires through B0(T+1) (covers next tile's p0/p1 reads). 4 regions
// = 8 loads stay in flight -> vmcnt(8) steady state; tail steps 8 -> 4 -> 0.
#define TILE_BODY(T, VM0, VM2, S0, S1, S2, S3) do { \
    const short* Ar0 = As + (((T) & 1) * 2 + 0) * RSH; \
    const short* Br0 = Bs + (((T) & 1) * 2 + 0) * RSH; \
    const short* Ar1 = As + (((T) & 1) * 2 + 1) * RSH; \
    const short* Br1 = Bs + (((T) & 1) * 2 + 1) * RSH; \
    /* p0: kk0, n01 */ \
    _Pragma("unroll") for (int m_ = 0; m_ < 8; ++m_) afr[m_] = ldsfrag32(Ar0, arow + m_ * 16, hi); \
    b0 = ldsfrag32(Br0, brow + 0, hi); b1 = ldsfrag32(Br0, brow + 16, hi); \
    if (S0) stage_region(Bop, Bs + ((((T) + 1) & 1) * 2 + 1) * RSH, w, l, ((T) + 1) * 64 + 32); \
    SBAR(); WAITVL(VM0); MFMA8x2(0); SBAR(); \
    /* p1: kk0, n23 */ \
    b0 = ldsfrag32(Br0, brow + 32, hi); b1 = ldsfrag32(Br0, brow + 48, hi); \
    if (S1) stage_region(Aop, As + (((T) & 1) * 2 + 0) * RSH, w, l, ((T) + 2) * 64); \
    SBAR(); WAITL(); MFMA8x2(2); SBAR(); \
    /* p2: kk1, n01 */ \
    _Pragma("unroll") for (int m_ = 0; m_ < 8; ++m_) afr[m_] = ldsfrag32(Ar1, arow + m_ * 16, hi); \
    b0 = ldsfrag32(Br1, brow + 0, hi); b1 = ldsfrag32(Br1, brow + 16, hi); \
    if (S2) stage_region(Bop, Bs + (((T) & 1) * 2 + 0) * RSH, w, l, ((T) + 2) * 64); \
    SBAR(); WAITVL(VM2); MFMA8x2(0); SBAR(); \
    /* p3: kk1, n23 */ \
    b0 = ldsfrag32(Br1, brow + 32, hi); b1 = ldsfrag32(Br1, brow + 48, hi); \
    if (S3) stage_region(Aop, As + (((T) & 1) * 2 + 1) * RSH, w, l, ((T) + 2) * 64 + 32); \
    SBAR(); WAITL(); MFMA8x2(2); SBAR(); \
} while (0)

// ---------------- fused 256^2 GEMM + per-tile partial LSE ----------------
// grid: 1280 blocks (16x16 tiles x 5 pairs), 512 threads (8 waves, 2M x 4N)
// m201-template 8-phase schedule (T2+T3+T4+T5): per phase ds_read || 1 region stage
// || barrier || counted vmcnt+lgkmcnt || 16 MFMA || barrier.
__launch_bounds__(512, 1)
__global__ void gemm_lse_kernel(const short* __restrict__ mats, const float* __restrict__ scale_p,
                                float* __restrict__ rowpart, float* __restrict__ colpart,
                                float* __restrict__ diag) {
    extern __shared__ char smem[];
    short* As = (short*)smem;                         // [2 buf][2 region][256][32]
    short* Bs = (short*)(smem + 65536);               // same
    float* rowLse = (float*)(smem + 131072);          // [4][256]
    float* colLse = rowLse + 4 * 256;                 // [2][256]

    const int tid = threadIdx.x;
    const int w = tid >> 6, l = tid & 63;
    const int wr = w >> 2, wc = w & 3;

    // bijective XCD swizzle: nwg = 1280 = 8 * 160
    const int orig = blockIdx.x;
    const int swz = (orig & 7) * 160 + (orig >> 3);
    const int p = swz >> 8;           // pair 0..4
    const int t = swz & 255;
    const int tileRow = t & 15, tileCol = t >> 4;

    // mats order: text(0) image(1) audio(2) depth(3); no stack arrays (rule #20)
    int ai, bi;
    switch (p) {
        case 0: ai = 2; bi = 0; break;
        case 1: ai = 2; bi = 1; break;
        case 2: ai = 3; bi = 0; break;
        case 3: ai = 3; bi = 1; break;
        default: ai = 0; bi = 1; break;
    }
    const short* Aop = mats + (size_t)ai * (BDIM * DDIM) + tileRow * 256 * DDIM;
    const short* Bop = mats + (size_t)bi * (BDIM * DDIM) + tileCol * 256 * DDIM;

    floatx4 acc[8][4];
#pragma unroll
    for (int m = 0; m < 8; ++m)
#pragma unroll
        for (int n = 0; n < 4; ++n) acc[m][n] = (floatx4)(0.f);

    const int fr = l & 15, hi = l >> 4;
    const int arow = wr * 128 + fr;   // + m*16
    const int brow = wc * 64 + fr;    // + n*16

    short8 afr[8], b0, b1;

    // prologue: 7 regions in ledger order, then retire the first tile's kk0 pair
    stage_region(Aop, As + 0 * RSH, w, l, 0);    // A0(0)
    stage_region(Bop, Bs + 0 * RSH, w, l, 0);    // B0(0)
    stage_region(Aop, As + 1 * RSH, w, l, 32);   // A1(0)
    stage_region(Bop, Bs + 1 * RSH, w, l, 32);   // B1(0)
    stage_region(Aop, As + 2 * RSH, w, l, 64);   // A0(1)
    stage_region(Bop, Bs + 2 * RSH, w, l, 64);   // B0(1)
    stage_region(Aop, As + 3 * RSH, w, l, 96);   // A1(1)
    asm volatile("s_waitcnt vmcnt(10)" ::: "memory");   // A0(0),B0(0) landed
    __builtin_amdgcn_s_barrier();

#pragma unroll 2
    for (int kt = 0; kt < 14; ++kt) TILE_BODY(kt, 8, 8, 1, 1, 1, 1);
    TILE_BODY(14, 8, 4, 1, 0, 0, 0);
    TILE_BODY(15, 0, 0, 0, 0, 0, 0);

    // scale (read AFTER the K-loop so no stray vector-mem op disturbs vmcnt counting)
    const float s = scale_p[0];
#pragma unroll
    for (int m = 0; m < 8; ++m)
#pragma unroll
        for (int n = 0; n < 4; ++n)
#pragma unroll
            for (int j = 0; j < 4; ++j) acc[m][n][j] *= s;

    // C/D layout: out[A-row: m*16+hi*4+j][B-row: n*16+fr] = acc[m][n][j]

    // ---- row partial LSE over this wave's 64 cols ----
#pragma unroll
    for (int m = 0; m < 8; ++m) {
#pragma unroll
        for (int j = 0; j < 4; ++j) {
            float mx = -3.0e38f;
#pragma unroll
            for (int n = 0; n < 4; ++n) mx = fmaxf(mx, acc[m][n][j]);
#pragma unroll
            for (int off = 1; off < 16; off <<= 1) mx = fmaxf(mx, __shfl_xor(mx, off));
            float sm = 0.f;
#pragma unroll
            for (int n = 0; n < 4; ++n) sm += __expf(acc[m][n][j] - mx);
#pragma unroll
            for (int off = 1; off < 16; off <<= 1) sm += __shfl_xor(sm, off);
            if (fr == 0)
                rowLse[wc * 256 + wr * 128 + m * 16 + hi * 4 + j] = mx + __logf(sm);
        }
    }

    // ---- col partial LSE over this wave's 128 rows ----
#pragma unroll
    for (int n = 0; n < 4; ++n) {
        float mx = -3.0e38f;
#pragma unroll
        for (int m = 0; m < 8; ++m)
#pragma unroll
            for (int j = 0; j < 4; ++j) mx = fmaxf(mx, acc[m][n][j]);
        mx = fmaxf(mx, __shfl_xor(mx, 16));
        mx = fmaxf(mx, __shfl_xor(mx, 32));
        float sm = 0.f;
#pragma unroll
        for (int m = 0; m < 8; ++m)
#pragma unroll
            for (int j = 0; j < 4; ++j) sm += __expf(acc[m][n][j] - mx);
        sm += __shfl_xor(sm, 16);
        sm += __shfl_xor(sm, 32);
        if (hi == 0)
            colLse[wr * 256 + wc * 64 + n * 16 + fr] = mx + __logf(sm);
    }

    // ---- diagonal: all acc[] array indices compile-time constant ----
    if (tileRow == tileCol && (wc >> 1) == wr) {
        if (hi == (fr >> 2)) {
            const int j = fr & 3;   // dynamic VECTOR lane only (select chain)
            float* dst = diag + p * BDIM + tileRow * 256 + wc * 64 + fr;
            if ((wc & 1) == 0) {
                dst[0]  = vsel4(acc[0][0], j);
                dst[16] = vsel4(acc[1][1], j);
                dst[32] = vsel4(acc[2][2], j);
                dst[48] = vsel4(acc[3][3], j);
            } else {
                dst[0]  = vsel4(acc[4][0], j);
                dst[16] = vsel4(acc[5][1], j);
                dst[32] = vsel4(acc[6][2], j);
                dst[48] = vsel4(acc[7][3], j);
            }
        }
    }

    __syncthreads();

    // combine partials: threads 0-255 rows, 256-511 cols
    if (tid < 256) {
        float v0 = rowLse[tid], v1 = rowLse[256 + tid], v2 = rowLse[512 + tid], v3 = rowLse[768 + tid];
        float mm = fmaxf(fmaxf(v0, v1), fmaxf(v2, v3));
        float r = mm + __logf(__expf(v0 - mm) + __expf(v1 - mm) + __expf(v2 - mm) + __expf(v3 - mm));
        rowpart[((size_t)p * BDIM + tileRow * 256 + tid) * TW + tileCol] = r;
    } else {
        int c = tid - 256;
        float v0 = colLse[c], v1 = colLse[256 + c];
        float mm = fmaxf(v0, v1);
        float r = mm + __logf(__expf(v0 - mm) + __expf(v1 - mm));
        colpart[((size_t)p * BDIM + tileCol * 256 + c) * TW + tileRow] = r;
    }
}

// ---------------- per-row final LSE + loss partial sums ----------------
__global__ void reduce_kernel(const float* __restrict__ rowpart, const float* __restrict__ colpart,
                              const float* __restrict__ diag, float* __restrict__ partials) {
    int p = blockIdx.y;
    int i = blockIdx.x * 256 + threadIdx.x;
    size_t gi = (size_t)p * BDIM + i;

    const float* rp = rowpart + gi * TW;
    float mx = -3.0e38f;
#pragma unroll
    for (int t = 0; t < TW; ++t) mx = fmaxf(mx, rp[t]);
    float sm = 0.f;
#pragma unroll
    for (int t = 0; t < TW; ++t) sm += __expf(rp[t] - mx);
    float rl = mx + __logf(sm);

    const float* cp = colpart + gi * TW;
    mx = -3.0e38f;
#pragma unroll
    for (int t = 0; t < TW; ++t) mx = fmaxf(mx, cp[t]);
    sm = 0.f;
#pragma unroll
    for (int t = 0; t < TW; ++t) sm += __expf(cp[t] - mx);
    float cl = mx + __logf(sm);

    float contrib = rl + cl - 2.f * diag[gi];

    __shared__ float red[256];
    red[threadIdx.x] = contrib;
    __syncthreads();
    for (int s2 = 128; s2 > 0; s2 >>= 1) {
        if (threadIdx.x < (unsigned)s2) red[threadIdx.x] += red[threadIdx.x + s2];
        __syncthreads();
    }
    if (threadIdx.x == 0) partials[p * 16 + blockIdx.x] = red[0];
}

__global__ void final_kernel(const float* __restrict__ partials, float* __restrict__ out) {
    __shared__ float red[128];
    int t = threadIdx.x;
    red[t] = (t < NPAIRS * 16) ? partials[t] : 0.f;
    __syncthreads();
    for (int s2 = 64; s2 > 0; s2 >>= 1) {
        if (t < s2) red[t] += red[t + s2];
        __syncthreads();
    }
    if (t == 0) out[0] = red[0] * (1.f / (2.f * BDIM));
}

extern "C" void kernel_launch(void* const* d_in, const int* in_sizes, int n_in,
                              void* d_out, int out_size, void* d_ws, size_t ws_size,
                              hipStream_t stream) {
    const float* text  = (const float*)d_in[0];
    const float* image = (const float*)d_in[1];
    const float* audio = (const float*)d_in[2];
    const float* depth = (const float*)d_in[3];
    const float* scale = (const float*)d_in[4];
    float* out = (float*)d_out;

    char* ws = (char*)d_ws;
    short* mats = (short*)ws;                                   // 4 * 8 MB bf16
    size_t off = (size_t)4 * BDIM * DDIM * 2;
    float* rowpart = (float*)(ws + off); off += (size_t)NPAIRS * BDIM * TW * 4;
    float* colpart = (float*)(ws + off); off += (size_t)NPAIRS * BDIM * TW * 4;
    float* diag    = (float*)(ws + off); off += (size_t)NPAIRS * BDIM * 4;
    float* partials= (float*)(ws + off); off += NPAIRS * 16 * 4;

    const int smem_bytes = 131072 + 4 * 256 * 4 + 2 * 256 * 4;  // 137216
    hipFuncSetAttribute((const void*)gemm_lse_kernel,
                        hipFuncAttributeMaxDynamicSharedMemorySize, smem_bytes);

    cast_kernel<<<dim3(2048, 4), 256, 0, stream>>>(text, image, audio, depth, mats);
    gemm_lse_kernel<<<dim3(1280), 512, smem_bytes, stream>>>(mats, scale, rowpart, colpart, diag);
    reduce_kernel<<<dim3(16, NPAIRS), 256, 0, stream>>>(rowpart, colpart, diag, partials);
    final_kernel<<<1, 128, 0, stream>>>(partials, out);
}